// Round 2
// baseline (528.150 us; speedup 1.0000x reference)
//
#include <hip/hip_runtime.h>
#include <hip/hip_bf16.h>

// Shapes: b=2,t=8,l=1024,c=256,h=8,d=32 -> NTOK=16384, BTH=128
// Inputs/outputs: float32. ws intermediates: _Float16.
// ws layout (f16): qn | kn | vt | xa, each 4194304 elems (8MB) -> 32MB
//   qn/kn/xa: [bth][l][32]; vt TRANSPOSED: [bth][32][l] with the k (column)
//   index bit-permuted (bits 2<->3 swapped within each 16-block) so that a
//   plain f16x8 load yields the PV A-fragment matching P's natural register
//   order after the swapped 32x32 QK^T (no P transpose needed at all).
//   W-f16 scratch (Wq|Wk|Wv, 3*65536) aliases the xa region: it is consumed
//   by proj_mfma before attn overwrites xa. Stream order guarantees safety.
// qn is pre-scaled by log2(e)/sqrt(32) so attn uses exp2 directly.

#define NTOK  16384
#define CDIM  256
#define LSEQ  1024
#define HEADS 8
#define DHEAD 32

typedef _Float16 f16;
typedef __attribute__((ext_vector_type(2))) _Float16 f16x2;
typedef __attribute__((ext_vector_type(4))) _Float16 f16x4;
typedef __attribute__((ext_vector_type(8))) _Float16 f16x8;
typedef __attribute__((ext_vector_type(4))) float f32x4;
typedef __attribute__((ext_vector_type(16))) float f32x16;

#define QSCALE (0.17677669529663687f * 1.4426950408889634f)  // 1/sqrt(32)*log2e

__device__ __forceinline__ f16x2 pkcvt(float a, float b) {
  auto r = __builtin_amdgcn_cvt_pkrtz(a, b);  // v_cvt_pkrtz_f16_f32
  union { decltype(r) in; f16x2 out; } u;
  u.in = r;
  return u.out;
}

// 8 consecutive f32 at p (32B-aligned) -> f16x8 fragment
__device__ __forceinline__ f16x8 cvt8(const float* p) {
  float4 a = *(const float4*)p;
  float4 b = *(const float4*)(p + 4);
  union { f16x8 v; f16x2 h[4]; } u;
  u.h[0] = pkcvt(a.x, a.y);
  u.h[1] = pkcvt(a.z, a.w);
  u.h[2] = pkcvt(b.x, b.y);
  u.h[3] = pkcvt(b.z, b.w);
  return u.v;
}

// ---------------------------------------------------------------------------
// Kernel 0: convert Wq|Wk|Wv (each 256x256 f32) to f16, packed consecutively.
// ---------------------------------------------------------------------------
__global__ __launch_bounds__(256)
void cvt_w_kernel(const float* __restrict__ Wq, const float* __restrict__ Wk,
                  const float* __restrict__ Wv, f16* __restrict__ dst) {
  const int m = blockIdx.x >> 6;  // matrix index
  const float* src = (m == 0) ? Wq : (m == 1) ? Wk : Wv;
  const int base = (blockIdx.x & 63) * 1024 + threadIdx.x * 4;
  float4 a = *(const float4*)(src + base);
  union { f16x4 v; f16x2 h[2]; } u;
  u.h[0] = pkcvt(a.x, a.y);
  u.h[1] = pkcvt(a.z, a.w);
  *(f16x4*)(dst + m * 65536 + base) = u.v;
}

// ---------------------------------------------------------------------------
// Kernel 1: fused Q/K/V projection + bias + per-head L2-norm via MFMA.
// Grid (256, 3): blockIdx.y selects tensor. Block = 4 waves, 64 tokens;
// wave w computes out-channels 64w..64w+63 (heads 2w, 2w+1) x 64 tokens.
// D[m=och][n=tok] = sum_k W[och][k] * x[tok][k]; both frags contiguous 16B.
// A = W f16 (pre-converted), B = x f32 -> f16 inline. No LDS, no barriers.
// C-layout: col=l16 -> token, row=quad*4+r -> och.
// V store: transposed [32][LSEQ] with column bits 2<->3 swapped (see header).
// ---------------------------------------------------------------------------
__global__ __launch_bounds__(256, 3)
void proj_mfma_kernel(const float* __restrict__ xq, const float* __restrict__ xk,
                      const float* __restrict__ xv, const f16* __restrict__ w16,
                      const float* __restrict__ bq, const float* __restrict__ bk,
                      const float* __restrict__ bv,
                      f16* __restrict__ qn, f16* __restrict__ kn,
                      f16* __restrict__ vt) {
  const int which = blockIdx.y;
  const float* x    = (which == 0) ? xq : (which == 1) ? xk : xv;
  const float* bias = (which == 0) ? bq : (which == 1) ? bk : bv;
  const f16* W      = w16 + which * 65536;
  f16* out          = (which == 0) ? qn : (which == 1) ? kn : vt;
  const float scale = (which == 0) ? QSCALE : 1.0f;
  const bool transposed = (which == 2);

  const int tid = threadIdx.x;
  const int wave = tid >> 6, lane = tid & 63;
  const int quad = lane >> 4, l16 = lane & 15;
  const int tokbase = blockIdx.x * 64;
  const int wbase = wave * 64;

  f32x4 acc[4][4];  // [m-tile][n-tile]
#pragma unroll
  for (int mt = 0; mt < 4; ++mt)
#pragma unroll
    for (int nt = 0; nt < 4; ++nt) acc[mt][nt] = (f32x4){0.f, 0.f, 0.f, 0.f};

#pragma unroll
  for (int kk = 0; kk < 8; ++kk) {
    f16x8 af[4], bf[4];
#pragma unroll
    for (int mt = 0; mt < 4; ++mt)
      af[mt] = *(const f16x8*)(W + (size_t)(wbase + mt * 16 + l16) * CDIM +
                               kk * 32 + quad * 8);
#pragma unroll
    for (int nt = 0; nt < 4; ++nt)
      bf[nt] = cvt8(x + (size_t)(tokbase + nt * 16 + l16) * CDIM + kk * 32 +
                    quad * 8);
#pragma unroll
    for (int mt = 0; mt < 4; ++mt)
#pragma unroll
      for (int nt = 0; nt < 4; ++nt)
        acc[mt][nt] = __builtin_amdgcn_mfma_f32_16x16x32_f16(af[mt], bf[nt],
                                                             acc[mt][nt], 0, 0, 0);
  }

  // epilogue: bias -> per-head L2 norm (d spans 2 m-tiles x 4 quads) -> store
  const int bt = tokbase >> 10, l0 = tokbase & 1023;
#pragma unroll
  for (int hh = 0; hh < 2; ++hh) {
    const int h = wave * 2 + hh;
    const size_t hb = (size_t)(bt * HEADS + h) * (LSEQ * DHEAD);
    float4 b0 = *(const float4*)(bias + wbase + hh * 32 + quad * 4);
    float4 b1 = *(const float4*)(bias + wbase + hh * 32 + 16 + quad * 4);
#pragma unroll
    for (int nt = 0; nt < 4; ++nt) {
      f32x4 a0 = acc[hh * 2 + 0][nt];
      f32x4 a1 = acc[hh * 2 + 1][nt];
      float v0[4], v1[4];
      v0[0] = a0[0] + b0.x; v0[1] = a0[1] + b0.y;
      v0[2] = a0[2] + b0.z; v0[3] = a0[3] + b0.w;
      v1[0] = a1[0] + b1.x; v1[1] = a1[1] + b1.y;
      v1[2] = a1[2] + b1.z; v1[3] = a1[3] + b1.w;
      float ss = 0.f;
#pragma unroll
      for (int r = 0; r < 4; ++r) ss += v0[r] * v0[r] + v1[r] * v1[r];
      ss += __shfl_xor(ss, 16);
      ss += __shfl_xor(ss, 32);
      const float inv = scale / fmaxf(sqrtf(ss), 1e-12f);
      const int tok_l = l0 + nt * 16 + l16;
      if (!transposed) {
        f16x4 o0, o1;
#pragma unroll
        for (int r = 0; r < 4; ++r) {
          o0[r] = (f16)(v0[r] * inv);
          o1[r] = (f16)(v1[r] * inv);
        }
        *(f16x4*)(out + hb + (size_t)tok_l * DHEAD + quad * 4) = o0;
        *(f16x4*)(out + hb + (size_t)tok_l * DHEAD + 16 + quad * 4) = o1;
      } else {
        // column index with bits 2<->3 swapped (within each 16-token block):
        // memory[col] holds token f(col); f is an involution.
        const int tcol = (tok_l & ~12) | ((tok_l & 4) << 1) | ((tok_l & 8) >> 1);
#pragma unroll
        for (int r = 0; r < 4; ++r) {
          out[hb + (size_t)(quad * 4 + r) * LSEQ + tcol] = (f16)(v0[r] * inv);
          out[hb + (size_t)(16 + quad * 4 + r) * LSEQ + tcol] = (f16)(v1[r] * inv);
        }
      }
    }
  }
}

// ---------------------------------------------------------------------------
// Kernel 2: attention via swapped 32x32x16 MFMA. No LDS, no barriers.
// Per wave: 32 q-rows. S^T = mfma(K, Q): lane (l32,hi) holds 16 scores of
// q-column l32 at k-rows (r&3)+8*(r>>2)+4*hi. exp2 -> packed f16 pairs form
// the PV B-fragment DIRECTLY; V^T was stored with matching k-permutation.
// Round 2: software-pipelined k-loop — register double-buffer (static
// indices via full unroll), next block's 4 global loads issued BEFORE the
// current block's QK->exp->PV chain so L2 latency hides under compute.
// ---------------------------------------------------------------------------
__global__ __launch_bounds__(256, 4)
void attn_mfma_kernel(const f16* __restrict__ qn,
                      const f16* __restrict__ kn,
                      const f16* __restrict__ vt,
                      f16* __restrict__ xo) {
  const int tid  = threadIdx.x;
  const int wave = tid >> 6, lane = tid & 63;
  const int l32 = lane & 31, hi = lane >> 5;
  // XCD-aware swizzle: all 8 q-chunk blocks of a head land on one XCD's L2.
  const int wid = (blockIdx.x & 7) * 128 + (blockIdx.x >> 3);
  const int bth = wid >> 3;
  const int qbase = ((wid & 7) << 7) + wave * 32;
  const size_t hb = (size_t)bth * (LSEQ * DHEAD);

  const f16* qp = qn + hb + (size_t)(qbase + l32) * DHEAD + hi * 8;
  const f16x8 qf0 = *(const f16x8*)qp;
  const f16x8 qf1 = *(const f16x8*)(qp + 16);

  const f16* kbase = kn + hb + (size_t)l32 * DHEAD + hi * 8;
  const f16* vbase = vt + hb + (size_t)l32 * LSEQ + hi * 8;

  f32x16 oacc, z16;
#pragma unroll
  for (int r = 0; r < 16; ++r) { oacc[r] = 0.f; z16[r] = 0.f; }
  float ls0 = 0.f, ls1 = 0.f;

  // Register double-buffer: slot = b&1 (compile-time after full unroll).
  f16x8 kb_[2][2], vb_[2][2];
  kb_[0][0] = *(const f16x8*)(kbase);
  kb_[0][1] = *(const f16x8*)(kbase + 16);
  vb_[0][0] = *(const f16x8*)(vbase);
  vb_[0][1] = *(const f16x8*)(vbase + 16);

#pragma unroll
  for (int b = 0; b < 32; ++b) {
    const int cur = b & 1, nxt = cur ^ 1;
    if (b + 1 < 32) {  // issue next block's loads before current compute
      const f16* kp = kbase + (size_t)(b + 1) * 32 * DHEAD;
      const f16* vp = vbase + (b + 1) * 32;
      kb_[nxt][0] = *(const f16x8*)(kp);
      kb_[nxt][1] = *(const f16x8*)(kp + 16);
      vb_[nxt][0] = *(const f16x8*)(vp);
      vb_[nxt][1] = *(const f16x8*)(vp + 16);
    }

    f32x16 s = __builtin_amdgcn_mfma_f32_32x32x16_f16(kb_[cur][0], qf0, z16,
                                                      0, 0, 0);
    s = __builtin_amdgcn_mfma_f32_32x32x16_f16(kb_[cur][1], qf1, s, 0, 0, 0);

    union { f16x8 v; f16x2 h[4]; } p0, p1;
#pragma unroll
    for (int i = 0; i < 4; ++i) {
      float e0 = __builtin_amdgcn_exp2f(s[2 * i]);
      float e1 = __builtin_amdgcn_exp2f(s[2 * i + 1]);
      ls0 += e0; ls1 += e1;
      p0.h[i] = pkcvt(e0, e1);
      float e2 = __builtin_amdgcn_exp2f(s[8 + 2 * i]);
      float e3 = __builtin_amdgcn_exp2f(s[9 + 2 * i]);
      ls0 += e2; ls1 += e3;
      p1.h[i] = pkcvt(e2, e3);
    }
    oacc = __builtin_amdgcn_mfma_f32_32x32x16_f16(vb_[cur][0], p0.v, oacc,
                                                  0, 0, 0);
    oacc = __builtin_amdgcn_mfma_f32_32x32x16_f16(vb_[cur][1], p1.v, oacc,
                                                  0, 0, 0);
  }

  float lsum = ls0 + ls1;        // own 16 k-rows
  lsum += __shfl_xor(lsum, 32);  // + partner half's 16 k-rows
  const float inv = __builtin_amdgcn_rcpf(lsum);

  f16* op = xo + hb + (size_t)(qbase + l32) * DHEAD + hi * 4;
#pragma unroll
  for (int g = 0; g < 4; ++g) {   // d-base = 8g + 4hi, 4 contiguous d each
    union { f16x4 v; f16x2 h[2]; } o;
    o.h[0] = pkcvt(oacc[4 * g + 0] * inv, oacc[4 * g + 1] * inv);
    o.h[1] = pkcvt(oacc[4 * g + 2] * inv, oacc[4 * g + 3] * inv);
    *(f16x4*)(op + 8 * g) = o.v;
  }
}

// ---------------------------------------------------------------------------
// Kernel 3: out = xatt @ Wm^T + bm + residual, f32 out, via MFMA.
// Same structure as proj_mfma; A = Wm inline f32->f16; k-step kk == head kk
// of xatt ([bth][l][32] is k-contiguous within a head). float4 stores.
// ---------------------------------------------------------------------------
__global__ __launch_bounds__(256, 3)
void out_proj_mfma_kernel(const f16* __restrict__ xatt,
                          const float* __restrict__ Wm,
                          const float* __restrict__ bm,
                          const float* __restrict__ resid,
                          float* __restrict__ out) {
  const int tid = threadIdx.x;
  const int wave = tid >> 6, lane = tid & 63;
  const int quad = lane >> 4, l16 = lane & 15;
  const int tokbase = blockIdx.x * 64;
  const int wbase = wave * 64;
  const int bt = tokbase >> 10, l0 = tokbase & 1023;

  f32x4 acc[4][4];
#pragma unroll
  for (int mt = 0; mt < 4; ++mt)
#pragma unroll
    for (int nt = 0; nt < 4; ++nt) acc[mt][nt] = (f32x4){0.f, 0.f, 0.f, 0.f};

#pragma unroll
  for (int kk = 0; kk < 8; ++kk) {
    const size_t hb = (size_t)(bt * HEADS + kk) * (LSEQ * DHEAD);
    f16x8 af[4], bf[4];
#pragma unroll
    for (int mt = 0; mt < 4; ++mt)
      af[mt] = cvt8(Wm + (size_t)(wbase + mt * 16 + l16) * CDIM + kk * 32 +
                    quad * 8);
#pragma unroll
    for (int nt = 0; nt < 4; ++nt)
      bf[nt] = *(const f16x8*)(xatt + hb +
                               (size_t)(l0 + nt * 16 + l16) * DHEAD + quad * 8);
#pragma unroll
    for (int mt = 0; mt < 4; ++mt)
#pragma unroll
      for (int nt = 0; nt < 4; ++nt)
        acc[mt][nt] = __builtin_amdgcn_mfma_f32_16x16x32_f16(af[mt], bf[nt],
                                                             acc[mt][nt], 0, 0, 0);
  }

#pragma unroll
  for (int mt = 0; mt < 4; ++mt) {
    float4 bv = *(const float4*)(bm + wbase + mt * 16 + quad * 4);
#pragma unroll
    for (int nt = 0; nt < 4; ++nt) {
      const int tok = tokbase + nt * 16 + l16;
      const size_t off = (size_t)tok * CDIM + wbase + mt * 16 + quad * 4;
      float4 rv = *(const float4*)(resid + off);
      float4 o;
      o.x = acc[mt][nt][0] + bv.x + rv.x;
      o.y = acc[mt][nt][1] + bv.y + rv.y;
      o.z = acc[mt][nt][2] + bv.z + rv.z;
      o.w = acc[mt][nt][3] + bv.w + rv.w;
      *(float4*)(out + off) = o;
    }
  }
}

extern "C" void kernel_launch(void* const* d_in, const int* in_sizes, int n_in,
                              void* d_out, int out_size, void* d_ws,
                              size_t ws_size, hipStream_t stream) {
  const float* q  = (const float*)d_in[0];
  const float* k  = (const float*)d_in[1];
  const float* v  = (const float*)d_in[2];
  const float* Wq = (const float*)d_in[3];
  const float* bq = (const float*)d_in[4];
  const float* Wk = (const float*)d_in[5];
  const float* bk = (const float*)d_in[6];
  const float* Wv = (const float*)d_in[7];
  const float* bv = (const float*)d_in[8];
  const float* Wm = (const float*)d_in[9];
  const float* bm = (const float*)d_in[10];
  float* outp = (float*)d_out;

  f16* ws = (f16*)d_ws;
  const size_t TENS = (size_t)NTOK * CDIM;  // 4194304
  f16* qn  = ws;
  f16* kn  = ws + TENS;
  f16* vt  = ws + 2 * TENS;
  f16* xa  = ws + 3 * TENS;
  f16* w16 = xa;  // alias: consumed by proj_mfma before attn writes xa

  dim3 blk(256);
  cvt_w_kernel<<<dim3(192), blk, 0, stream>>>(Wq, Wk, Wv, w16);
  proj_mfma_kernel<<<dim3(256, 3), blk, 0, stream>>>(q, k, v, w16, bq, bk, bv,
                                                     qn, kn, vt);
  attn_mfma_kernel<<<dim3(1024), blk, 0, stream>>>(qn, kn, vt, xa);
  out_proj_mfma_kernel<<<dim3(256), blk, 0, stream>>>(xa, Wm, bm, q, outp);
}

// Round 3
// 204.951 us; speedup vs baseline: 2.5770x; 2.5770x over previous
//
#include <hip/hip_runtime.h>
#include <hip/hip_bf16.h>

// Shapes: b=2,t=8,l=1024,c=256,h=8,d=32 -> NTOK=16384, BTH=128
// Inputs/outputs: float32. ws intermediates: _Float16.
// ws layout (f16): qn | kn | vt | xa, each 4194304 elems (8MB) -> 32MB
//   qn/kn/xa: [bth][l][32]; vt TRANSPOSED: [bth][32][l] with the k (column)
//   index bit-permuted (bits 2<->3 swapped within each 16-block) so that a
//   plain f16x8 load yields the PV A-fragment matching P's natural register
//   order after the swapped 32x32 QK^T (no P transpose needed at all).
//   W-f16 scratch (Wq|Wk|Wv, 3*65536) aliases the xa region: it is consumed
//   by proj_mfma before attn overwrites xa. Stream order guarantees safety.
// qn is pre-scaled by log2(e)/sqrt(32) so attn uses exp2 directly.

#define NTOK  16384
#define CDIM  256
#define LSEQ  1024
#define HEADS 8
#define DHEAD 32

typedef _Float16 f16;
typedef __attribute__((ext_vector_type(2))) _Float16 f16x2;
typedef __attribute__((ext_vector_type(4))) _Float16 f16x4;
typedef __attribute__((ext_vector_type(8))) _Float16 f16x8;
typedef __attribute__((ext_vector_type(4))) float f32x4;
typedef __attribute__((ext_vector_type(16))) float f32x16;

#define QSCALE (0.17677669529663687f * 1.4426950408889634f)  // 1/sqrt(32)*log2e

__device__ __forceinline__ f16x2 pkcvt(float a, float b) {
  auto r = __builtin_amdgcn_cvt_pkrtz(a, b);  // v_cvt_pkrtz_f16_f32
  union { decltype(r) in; f16x2 out; } u;
  u.in = r;
  return u.out;
}

// 8 consecutive f32 at p (32B-aligned) -> f16x8 fragment
__device__ __forceinline__ f16x8 cvt8(const float* p) {
  float4 a = *(const float4*)p;
  float4 b = *(const float4*)(p + 4);
  union { f16x8 v; f16x2 h[4]; } u;
  u.h[0] = pkcvt(a.x, a.y);
  u.h[1] = pkcvt(a.z, a.w);
  u.h[2] = pkcvt(b.x, b.y);
  u.h[3] = pkcvt(b.z, b.w);
  return u.v;
}

// ---------------------------------------------------------------------------
// Kernel 0: convert Wq|Wk|Wv (each 256x256 f32) to f16, packed consecutively.
// ---------------------------------------------------------------------------
__global__ __launch_bounds__(256)
void cvt_w_kernel(const float* __restrict__ Wq, const float* __restrict__ Wk,
                  const float* __restrict__ Wv, f16* __restrict__ dst) {
  const int m = blockIdx.x >> 6;  // matrix index
  const float* src = (m == 0) ? Wq : (m == 1) ? Wk : Wv;
  const int base = (blockIdx.x & 63) * 1024 + threadIdx.x * 4;
  float4 a = *(const float4*)(src + base);
  union { f16x4 v; f16x2 h[2]; } u;
  u.h[0] = pkcvt(a.x, a.y);
  u.h[1] = pkcvt(a.z, a.w);
  *(f16x4*)(dst + m * 65536 + base) = u.v;
}

// ---------------------------------------------------------------------------
// Kernel 1: fused Q/K/V projection + bias + per-head L2-norm via MFMA.
// Grid (256, 3): blockIdx.y selects tensor. Block = 4 waves, 64 tokens;
// wave w computes out-channels 64w..64w+63 (heads 2w, 2w+1) x 64 tokens.
// D[m=och][n=tok] = sum_k W[och][k] * x[tok][k]; both frags contiguous 16B.
// A = W f16 (pre-converted), B = x f32 -> f16 inline. No LDS, no barriers.
// C-layout: col=l16 -> token, row=quad*4+r -> och.
// V store: transposed [32][LSEQ] with column bits 2<->3 swapped (see header).
// ---------------------------------------------------------------------------
__global__ __launch_bounds__(256, 3)
void proj_mfma_kernel(const float* __restrict__ xq, const float* __restrict__ xk,
                      const float* __restrict__ xv, const f16* __restrict__ w16,
                      const float* __restrict__ bq, const float* __restrict__ bk,
                      const float* __restrict__ bv,
                      f16* __restrict__ qn, f16* __restrict__ kn,
                      f16* __restrict__ vt) {
  const int which = blockIdx.y;
  const float* x    = (which == 0) ? xq : (which == 1) ? xk : xv;
  const float* bias = (which == 0) ? bq : (which == 1) ? bk : bv;
  const f16* W      = w16 + which * 65536;
  f16* out          = (which == 0) ? qn : (which == 1) ? kn : vt;
  const float scale = (which == 0) ? QSCALE : 1.0f;
  const bool transposed = (which == 2);

  const int tid = threadIdx.x;
  const int wave = tid >> 6, lane = tid & 63;
  const int quad = lane >> 4, l16 = lane & 15;
  const int tokbase = blockIdx.x * 64;
  const int wbase = wave * 64;

  f32x4 acc[4][4];  // [m-tile][n-tile]
#pragma unroll
  for (int mt = 0; mt < 4; ++mt)
#pragma unroll
    for (int nt = 0; nt < 4; ++nt) acc[mt][nt] = (f32x4){0.f, 0.f, 0.f, 0.f};

#pragma unroll
  for (int kk = 0; kk < 8; ++kk) {
    f16x8 af[4], bf[4];
#pragma unroll
    for (int mt = 0; mt < 4; ++mt)
      af[mt] = *(const f16x8*)(W + (size_t)(wbase + mt * 16 + l16) * CDIM +
                               kk * 32 + quad * 8);
#pragma unroll
    for (int nt = 0; nt < 4; ++nt)
      bf[nt] = cvt8(x + (size_t)(tokbase + nt * 16 + l16) * CDIM + kk * 32 +
                    quad * 8);
#pragma unroll
    for (int mt = 0; mt < 4; ++mt)
#pragma unroll
      for (int nt = 0; nt < 4; ++nt)
        acc[mt][nt] = __builtin_amdgcn_mfma_f32_16x16x32_f16(af[mt], bf[nt],
                                                             acc[mt][nt], 0, 0, 0);
  }

  // epilogue: bias -> per-head L2 norm (d spans 2 m-tiles x 4 quads) -> store
  const int bt = tokbase >> 10, l0 = tokbase & 1023;
#pragma unroll
  for (int hh = 0; hh < 2; ++hh) {
    const int h = wave * 2 + hh;
    const size_t hb = (size_t)(bt * HEADS + h) * (LSEQ * DHEAD);
    float4 b0 = *(const float4*)(bias + wbase + hh * 32 + quad * 4);
    float4 b1 = *(const float4*)(bias + wbase + hh * 32 + 16 + quad * 4);
#pragma unroll
    for (int nt = 0; nt < 4; ++nt) {
      f32x4 a0 = acc[hh * 2 + 0][nt];
      f32x4 a1 = acc[hh * 2 + 1][nt];
      float v0[4], v1[4];
      v0[0] = a0[0] + b0.x; v0[1] = a0[1] + b0.y;
      v0[2] = a0[2] + b0.z; v0[3] = a0[3] + b0.w;
      v1[0] = a1[0] + b1.x; v1[1] = a1[1] + b1.y;
      v1[2] = a1[2] + b1.z; v1[3] = a1[3] + b1.w;
      float ss = 0.f;
#pragma unroll
      for (int r = 0; r < 4; ++r) ss += v0[r] * v0[r] + v1[r] * v1[r];
      ss += __shfl_xor(ss, 16);
      ss += __shfl_xor(ss, 32);
      const float inv = scale / fmaxf(sqrtf(ss), 1e-12f);
      const int tok_l = l0 + nt * 16 + l16;
      if (!transposed) {
        f16x4 o0, o1;
#pragma unroll
        for (int r = 0; r < 4; ++r) {
          o0[r] = (f16)(v0[r] * inv);
          o1[r] = (f16)(v1[r] * inv);
        }
        *(f16x4*)(out + hb + (size_t)tok_l * DHEAD + quad * 4) = o0;
        *(f16x4*)(out + hb + (size_t)tok_l * DHEAD + 16 + quad * 4) = o1;
      } else {
        // column index with bits 2<->3 swapped (within each 16-token block):
        // memory[col] holds token f(col); f is an involution.
        const int tcol = (tok_l & ~12) | ((tok_l & 4) << 1) | ((tok_l & 8) >> 1);
#pragma unroll
        for (int r = 0; r < 4; ++r) {
          out[hb + (size_t)(quad * 4 + r) * LSEQ + tcol] = (f16)(v0[r] * inv);
          out[hb + (size_t)(16 + quad * 4 + r) * LSEQ + tcol] = (f16)(v1[r] * inv);
        }
      }
    }
  }
}

// ---------------------------------------------------------------------------
// Kernel 2: attention via swapped 32x32x16 MFMA. No LDS, no barriers.
// Per wave: 32 q-rows. S^T = mfma(K, Q): lane (l32,hi) holds 16 scores of
// q-column l32 at k-rows (r&3)+8*(r>>2)+4*hi. exp2 -> packed f16 pairs form
// the PV B-fragment DIRECTLY; V^T was stored with matching k-permutation.
// Round 3: software pipeline with NAMED scalar buffers only (round 2's
// array-indexed buffers were allocated to scratch -> 900MB spill traffic,
// rule #20). Two k-blocks per iteration; the K-regs of block b are dead
// right after its two QK MFMAs, so the reload for block b+2 issues there
// and its latency hides under exp/PV/next-QK (~300+ own-wave cycles, x4
// waves TLP).
// ---------------------------------------------------------------------------
__global__ __launch_bounds__(256, 4)
void attn_mfma_kernel(const f16* __restrict__ qn,
                      const f16* __restrict__ kn,
                      const f16* __restrict__ vt,
                      f16* __restrict__ xo) {
  const int tid  = threadIdx.x;
  const int wave = tid >> 6, lane = tid & 63;
  const int l32 = lane & 31, hi = lane >> 5;
  // XCD-aware swizzle: all 8 q-chunk blocks of a head land on one XCD's L2.
  const int wid = (blockIdx.x & 7) * 128 + (blockIdx.x >> 3);
  const int bth = wid >> 3;
  const int qbase = ((wid & 7) << 7) + wave * 32;
  const size_t hb = (size_t)bth * (LSEQ * DHEAD);

  const f16* qp = qn + hb + (size_t)(qbase + l32) * DHEAD + hi * 8;
  const f16x8 qf0 = *(const f16x8*)qp;
  const f16x8 qf1 = *(const f16x8*)(qp + 16);

  const f16* kbase = kn + hb + (size_t)l32 * DHEAD + hi * 8;
  const f16* vbase = vt + hb + (size_t)l32 * LSEQ + hi * 8;

  f32x16 oacc, z16;
#pragma unroll
  for (int r = 0; r < 16; ++r) { oacc[r] = 0.f; z16[r] = 0.f; }
  float ls0 = 0.f, ls1 = 0.f;

#define LDK(d0, d1, blk) { const f16* _p = kbase + (size_t)(blk) * (32 * DHEAD); \
    d0 = *(const f16x8*)_p; d1 = *(const f16x8*)(_p + 16); }
#define LDV(d0, d1, blk) { const f16* _p = vbase + (size_t)(blk) * 32; \
    d0 = *(const f16x8*)_p; d1 = *(const f16x8*)(_p + 16); }
#define EXPPV(s, v0, v1) { \
    union { f16x8 v; f16x2 h[4]; } _q0, _q1; \
    _Pragma("unroll") \
    for (int i = 0; i < 4; ++i) { \
      float e0 = __builtin_amdgcn_exp2f(s[2 * i]); \
      float e1 = __builtin_amdgcn_exp2f(s[2 * i + 1]); \
      ls0 += e0; ls1 += e1; \
      _q0.h[i] = pkcvt(e0, e1); \
      float e2 = __builtin_amdgcn_exp2f(s[8 + 2 * i]); \
      float e3 = __builtin_amdgcn_exp2f(s[9 + 2 * i]); \
      ls0 += e2; ls1 += e3; \
      _q1.h[i] = pkcvt(e2, e3); \
    } \
    oacc = __builtin_amdgcn_mfma_f32_32x32x16_f16(v0, _q0.v, oacc, 0, 0, 0); \
    oacc = __builtin_amdgcn_mfma_f32_32x32x16_f16(v1, _q1.v, oacc, 0, 0, 0); }

  // Named double-buffer: set A = even blocks, set B = odd blocks.
  f16x8 ka0, ka1, va0, va1, kb0, kb1, vb0, vb1;
  LDK(ka0, ka1, 0) LDV(va0, va1, 0)
  LDK(kb0, kb1, 1) LDV(vb0, vb1, 1)

  for (int b = 0; b < 32; b += 2) {
    {
      f32x16 sA = __builtin_amdgcn_mfma_f32_32x32x16_f16(ka0, qf0, z16, 0, 0, 0);
      sA = __builtin_amdgcn_mfma_f32_32x32x16_f16(ka1, qf1, sA, 0, 0, 0);
      if (b + 2 < 32) LDK(ka0, ka1, b + 2)   // ka dead after QK -> refill now
      EXPPV(sA, va0, va1)
      if (b + 2 < 32) LDV(va0, va1, b + 2)   // va dead after PV -> refill
    }
    {
      f32x16 sB = __builtin_amdgcn_mfma_f32_32x32x16_f16(kb0, qf0, z16, 0, 0, 0);
      sB = __builtin_amdgcn_mfma_f32_32x32x16_f16(kb1, qf1, sB, 0, 0, 0);
      if (b + 3 < 32) LDK(kb0, kb1, b + 3)
      EXPPV(sB, vb0, vb1)
      if (b + 3 < 32) LDV(vb0, vb1, b + 3)
    }
  }
#undef LDK
#undef LDV
#undef EXPPV

  float lsum = ls0 + ls1;        // own 16 k-rows
  lsum += __shfl_xor(lsum, 32);  // + partner half's 16 k-rows
  const float inv = __builtin_amdgcn_rcpf(lsum);

  f16* op = xo + hb + (size_t)(qbase + l32) * DHEAD + hi * 4;
#pragma unroll
  for (int g = 0; g < 4; ++g) {   // d-base = 8g + 4hi, 4 contiguous d each
    union { f16x4 v; f16x2 h[2]; } o;
    o.h[0] = pkcvt(oacc[4 * g + 0] * inv, oacc[4 * g + 1] * inv);
    o.h[1] = pkcvt(oacc[4 * g + 2] * inv, oacc[4 * g + 3] * inv);
    *(f16x4*)(op + 8 * g) = o.v;
  }
}

// ---------------------------------------------------------------------------
// Kernel 3: out = xatt @ Wm^T + bm + residual, f32 out, via MFMA.
// Same structure as proj_mfma; A = Wm inline f32->f16; k-step kk == head kk
// of xatt ([bth][l][32] is k-contiguous within a head). float4 stores.
// ---------------------------------------------------------------------------
__global__ __launch_bounds__(256, 3)
void out_proj_mfma_kernel(const f16* __restrict__ xatt,
                          const float* __restrict__ Wm,
                          const float* __restrict__ bm,
                          const float* __restrict__ resid,
                          float* __restrict__ out) {
  const int tid = threadIdx.x;
  const int wave = tid >> 6, lane = tid & 63;
  const int quad = lane >> 4, l16 = lane & 15;
  const int tokbase = blockIdx.x * 64;
  const int wbase = wave * 64;
  const int bt = tokbase >> 10, l0 = tokbase & 1023;

  f32x4 acc[4][4];
#pragma unroll
  for (int mt = 0; mt < 4; ++mt)
#pragma unroll
    for (int nt = 0; nt < 4; ++nt) acc[mt][nt] = (f32x4){0.f, 0.f, 0.f, 0.f};

#pragma unroll
  for (int kk = 0; kk < 8; ++kk) {
    const size_t hb = (size_t)(bt * HEADS + kk) * (LSEQ * DHEAD);
    f16x8 af[4], bf[4];
#pragma unroll
    for (int mt = 0; mt < 4; ++mt)
      af[mt] = cvt8(Wm + (size_t)(wbase + mt * 16 + l16) * CDIM + kk * 32 +
                    quad * 8);
#pragma unroll
    for (int nt = 0; nt < 4; ++nt)
      bf[nt] = *(const f16x8*)(xatt + hb +
                               (size_t)(l0 + nt * 16 + l16) * DHEAD + quad * 8);
#pragma unroll
    for (int mt = 0; mt < 4; ++mt)
#pragma unroll
      for (int nt = 0; nt < 4; ++nt)
        acc[mt][nt] = __builtin_amdgcn_mfma_f32_16x16x32_f16(af[mt], bf[nt],
                                                             acc[mt][nt], 0, 0, 0);
  }

#pragma unroll
  for (int mt = 0; mt < 4; ++mt) {
    float4 bv = *(const float4*)(bm + wbase + mt * 16 + quad * 4);
#pragma unroll
    for (int nt = 0; nt < 4; ++nt) {
      const int tok = tokbase + nt * 16 + l16;
      const size_t off = (size_t)tok * CDIM + wbase + mt * 16 + quad * 4;
      float4 rv = *(const float4*)(resid + off);
      float4 o;
      o.x = acc[mt][nt][0] + bv.x + rv.x;
      o.y = acc[mt][nt][1] + bv.y + rv.y;
      o.z = acc[mt][nt][2] + bv.z + rv.z;
      o.w = acc[mt][nt][3] + bv.w + rv.w;
      *(float4*)(out + off) = o;
    }
  }
}

extern "C" void kernel_launch(void* const* d_in, const int* in_sizes, int n_in,
                              void* d_out, int out_size, void* d_ws,
                              size_t ws_size, hipStream_t stream) {
  const float* q  = (const float*)d_in[0];
  const float* k  = (const float*)d_in[1];
  const float* v  = (const float*)d_in[2];
  const float* Wq = (const float*)d_in[3];
  const float* bq = (const float*)d_in[4];
  const float* Wk = (const float*)d_in[5];
  const float* bk = (const float*)d_in[6];
  const float* Wv = (const float*)d_in[7];
  const float* bv = (const float*)d_in[8];
  const float* Wm = (const float*)d_in[9];
  const float* bm = (const float*)d_in[10];
  float* outp = (float*)d_out;

  f16* ws = (f16*)d_ws;
  const size_t TENS = (size_t)NTOK * CDIM;  // 4194304
  f16* qn  = ws;
  f16* kn  = ws + TENS;
  f16* vt  = ws + 2 * TENS;
  f16* xa  = ws + 3 * TENS;
  f16* w16 = xa;  // alias: consumed by proj_mfma before attn writes xa

  dim3 blk(256);
  cvt_w_kernel<<<dim3(192), blk, 0, stream>>>(Wq, Wk, Wv, w16);
  proj_mfma_kernel<<<dim3(256, 3), blk, 0, stream>>>(q, k, v, w16, bq, bk, bv,
                                                     qn, kn, vt);
  attn_mfma_kernel<<<dim3(1024), blk, 0, stream>>>(qn, kn, vt, xa);
  out_proj_mfma_kernel<<<dim3(256), blk, 0, stream>>>(xa, Wm, bm, q, outp);
}

// Round 4
// 183.288 us; speedup vs baseline: 2.8815x; 1.1182x over previous
//
#include <hip/hip_runtime.h>
#include <hip/hip_bf16.h>

// Shapes: b=2,t=8,l=1024,c=256,h=8,d=32 -> NTOK=16384, BTH=128
// Inputs/outputs: float32. ws intermediates: _Float16.
// ws layout (f16): qn | kn | vt | xa, each 4194304 elems (8MB) -> 32MB
//   qn/kn/xa: [bth][l][32]; vt TRANSPOSED: [bth][32][l] with the k (column)
//   index bit-permuted (bits 2<->3 swapped within each 16-block) so that a
//   plain f16x8 load yields the PV A-fragment matching P's natural register
//   order after the swapped 32x32 QK^T (no P transpose needed at all).
//   W-f16 scratch (Wq|Wk|Wv, 3*65536) aliases the xa region: it is consumed
//   by proj_mfma before attn overwrites xa. Stream order guarantees safety.
// qn is pre-scaled by log2(e)/sqrt(32) so attn uses exp2 directly.

#define NTOK  16384
#define CDIM  256
#define LSEQ  1024
#define HEADS 8
#define DHEAD 32

typedef _Float16 f16;
typedef __attribute__((ext_vector_type(2))) _Float16 f16x2;
typedef __attribute__((ext_vector_type(4))) _Float16 f16x4;
typedef __attribute__((ext_vector_type(8))) _Float16 f16x8;
typedef __attribute__((ext_vector_type(4))) float f32x4;
typedef __attribute__((ext_vector_type(16))) float f32x16;

#define QSCALE (0.17677669529663687f * 1.4426950408889634f)  // 1/sqrt(32)*log2e

__device__ __forceinline__ f16x2 pkcvt(float a, float b) {
  auto r = __builtin_amdgcn_cvt_pkrtz(a, b);  // v_cvt_pkrtz_f16_f32
  union { decltype(r) in; f16x2 out; } u;
  u.in = r;
  return u.out;
}

// 8 consecutive f32 at p (32B-aligned) -> f16x8 fragment
__device__ __forceinline__ f16x8 cvt8(const float* p) {
  float4 a = *(const float4*)p;
  float4 b = *(const float4*)(p + 4);
  union { f16x8 v; f16x2 h[4]; } u;
  u.h[0] = pkcvt(a.x, a.y);
  u.h[1] = pkcvt(a.z, a.w);
  u.h[2] = pkcvt(b.x, b.y);
  u.h[3] = pkcvt(b.z, b.w);
  return u.v;
}

// ---------------------------------------------------------------------------
// Kernel 0: convert Wq|Wk|Wv (each 256x256 f32) to f16, packed consecutively.
// ---------------------------------------------------------------------------
__global__ __launch_bounds__(256)
void cvt_w_kernel(const float* __restrict__ Wq, const float* __restrict__ Wk,
                  const float* __restrict__ Wv, f16* __restrict__ dst) {
  const int m = blockIdx.x >> 6;  // matrix index
  const float* src = (m == 0) ? Wq : (m == 1) ? Wk : Wv;
  const int base = (blockIdx.x & 63) * 1024 + threadIdx.x * 4;
  float4 a = *(const float4*)(src + base);
  union { f16x4 v; f16x2 h[2]; } u;
  u.h[0] = pkcvt(a.x, a.y);
  u.h[1] = pkcvt(a.z, a.w);
  *(f16x4*)(dst + m * 65536 + base) = u.v;
}

// ---------------------------------------------------------------------------
// Kernel 1: fused Q/K/V projection + bias + per-head L2-norm via MFMA.
// Grid (256, 3): blockIdx.y selects tensor. Block = 4 waves, 64 tokens;
// wave w computes out-channels 64w..64w+63 (heads 2w, 2w+1) x 64 tokens.
// D[m=och][n=tok] = sum_k W[och][k] * x[tok][k]; both frags contiguous 16B.
// A = W f16 (pre-converted), B = x f32 -> f16 inline. No LDS, no barriers.
// C-layout: col=l16 -> token, row=quad*4+r -> och.
// V store: transposed [32][LSEQ] with column bits 2<->3 swapped (see header).
// ---------------------------------------------------------------------------
__global__ __launch_bounds__(256, 3)
void proj_mfma_kernel(const float* __restrict__ xq, const float* __restrict__ xk,
                      const float* __restrict__ xv, const f16* __restrict__ w16,
                      const float* __restrict__ bq, const float* __restrict__ bk,
                      const float* __restrict__ bv,
                      f16* __restrict__ qn, f16* __restrict__ kn,
                      f16* __restrict__ vt) {
  const int which = blockIdx.y;
  const float* x    = (which == 0) ? xq : (which == 1) ? xk : xv;
  const float* bias = (which == 0) ? bq : (which == 1) ? bk : bv;
  const f16* W      = w16 + which * 65536;
  f16* out          = (which == 0) ? qn : (which == 1) ? kn : vt;
  const float scale = (which == 0) ? QSCALE : 1.0f;
  const bool transposed = (which == 2);

  const int tid = threadIdx.x;
  const int wave = tid >> 6, lane = tid & 63;
  const int quad = lane >> 4, l16 = lane & 15;
  const int tokbase = blockIdx.x * 64;
  const int wbase = wave * 64;

  f32x4 acc[4][4];  // [m-tile][n-tile]
#pragma unroll
  for (int mt = 0; mt < 4; ++mt)
#pragma unroll
    for (int nt = 0; nt < 4; ++nt) acc[mt][nt] = (f32x4){0.f, 0.f, 0.f, 0.f};

#pragma unroll
  for (int kk = 0; kk < 8; ++kk) {
    f16x8 af[4], bf[4];
#pragma unroll
    for (int mt = 0; mt < 4; ++mt)
      af[mt] = *(const f16x8*)(W + (size_t)(wbase + mt * 16 + l16) * CDIM +
                               kk * 32 + quad * 8);
#pragma unroll
    for (int nt = 0; nt < 4; ++nt)
      bf[nt] = cvt8(x + (size_t)(tokbase + nt * 16 + l16) * CDIM + kk * 32 +
                    quad * 8);
#pragma unroll
    for (int mt = 0; mt < 4; ++mt)
#pragma unroll
      for (int nt = 0; nt < 4; ++nt)
        acc[mt][nt] = __builtin_amdgcn_mfma_f32_16x16x32_f16(af[mt], bf[nt],
                                                             acc[mt][nt], 0, 0, 0);
  }

  // epilogue: bias -> per-head L2 norm (d spans 2 m-tiles x 4 quads) -> store
  const int bt = tokbase >> 10, l0 = tokbase & 1023;
#pragma unroll
  for (int hh = 0; hh < 2; ++hh) {
    const int h = wave * 2 + hh;
    const size_t hb = (size_t)(bt * HEADS + h) * (LSEQ * DHEAD);
    float4 b0 = *(const float4*)(bias + wbase + hh * 32 + quad * 4);
    float4 b1 = *(const float4*)(bias + wbase + hh * 32 + 16 + quad * 4);
#pragma unroll
    for (int nt = 0; nt < 4; ++nt) {
      f32x4 a0 = acc[hh * 2 + 0][nt];
      f32x4 a1 = acc[hh * 2 + 1][nt];
      float v0[4], v1[4];
      v0[0] = a0[0] + b0.x; v0[1] = a0[1] + b0.y;
      v0[2] = a0[2] + b0.z; v0[3] = a0[3] + b0.w;
      v1[0] = a1[0] + b1.x; v1[1] = a1[1] + b1.y;
      v1[2] = a1[2] + b1.z; v1[3] = a1[3] + b1.w;
      float ss = 0.f;
#pragma unroll
      for (int r = 0; r < 4; ++r) ss += v0[r] * v0[r] + v1[r] * v1[r];
      ss += __shfl_xor(ss, 16);
      ss += __shfl_xor(ss, 32);
      const float inv = scale / fmaxf(sqrtf(ss), 1e-12f);
      const int tok_l = l0 + nt * 16 + l16;
      if (!transposed) {
        f16x4 o0, o1;
#pragma unroll
        for (int r = 0; r < 4; ++r) {
          o0[r] = (f16)(v0[r] * inv);
          o1[r] = (f16)(v1[r] * inv);
        }
        *(f16x4*)(out + hb + (size_t)tok_l * DHEAD + quad * 4) = o0;
        *(f16x4*)(out + hb + (size_t)tok_l * DHEAD + 16 + quad * 4) = o1;
      } else {
        // column index with bits 2<->3 swapped (within each 16-token block):
        // memory[col] holds token f(col); f is an involution.
        const int tcol = (tok_l & ~12) | ((tok_l & 4) << 1) | ((tok_l & 8) >> 1);
#pragma unroll
        for (int r = 0; r < 4; ++r) {
          out[hb + (size_t)(quad * 4 + r) * LSEQ + tcol] = (f16)(v0[r] * inv);
          out[hb + (size_t)(16 + quad * 4 + r) * LSEQ + tcol] = (f16)(v1[r] * inv);
        }
      }
    }
  }
}

// ---------------------------------------------------------------------------
// Kernel 2: attention via swapped 32x32x16 MFMA.
// Round 4: K/V staged through LDS, shared by the block's 4 waves (they read
// IDENTICAL K/V). Rationale: rounds 1/3 both sat at ~53us with ~65% no-issue
// cycles; the strided 16B-at-64B-stride per-wave loads touch 32 cache lines
// per instruction and are 4x redundant across waves -> L1/TA line-throughput
// limit. Staging: dense contiguous global loads (64 lanes x 16B), padded LDS
// rows (K 80B, V 144B: 16B-aligned, 8-dword/bank floor on write and read),
// double-buffered; loads for tile t+2 issue right after the t+1 ds_write so
// latency hides under a full tile's compute. Math/fragments unchanged.
// ---------------------------------------------------------------------------
#define TKROW 40  // padded K row, f16 units (64 rows/tile)
#define TVROW 72  // padded V row, f16 units (32 rows, 64 k-cols/tile)

__global__ __launch_bounds__(256, 4)
void attn_mfma_kernel(const f16* __restrict__ qn,
                      const f16* __restrict__ kn,
                      const f16* __restrict__ vt,
                      f16* __restrict__ xo) {
  __shared__ f16 kl[2][64 * TKROW];  // 2 x 5120B
  __shared__ f16 vl[2][32 * TVROW];  // 2 x 4608B
  const int tid  = threadIdx.x;
  const int wave = tid >> 6, lane = tid & 63;
  const int l32 = lane & 31, hi = lane >> 5;
  // XCD-aware swizzle: all 8 q-chunk blocks of a head land on one XCD's L2.
  const int wid = (blockIdx.x & 7) * 128 + (blockIdx.x >> 3);
  const int bth = wid >> 3;
  const int qbase = ((wid & 7) << 7) + wave * 32;
  const size_t hb = (size_t)bth * (LSEQ * DHEAD);

  const f16* qp = qn + hb + (size_t)(qbase + l32) * DHEAD + hi * 8;
  const f16x8 qf0 = *(const f16x8*)qp;
  const f16x8 qf1 = *(const f16x8*)(qp + 16);

  // staging split: wave w stages K rows 16w..16w+15 (4 lanes/row, 16B chunks)
  // and V rows 8w..8w+7 (8 lanes/row, 16B chunks). Dense 1KB per wave-load.
  const int krow_w = wave * 16 + (lane >> 2), kcol = (lane & 3) * 8;
  const int vrow_w = wave * 8 + (lane >> 3), vcol = (lane & 7) * 8;
  const f16* gK = kn + hb + (size_t)krow_w * DHEAD + kcol;  // + t*64*DHEAD
  const f16* gV = vt + hb + (size_t)vrow_w * LSEQ + vcol;   // + t*64
  const int lK = krow_w * TKROW + kcol;
  const int lV = vrow_w * TVROW + vcol;

  f32x16 oacc, z16;
#pragma unroll
  for (int r = 0; r < 16; ++r) { oacc[r] = 0.f; z16[r] = 0.f; }
  float ls0 = 0.f, ls1 = 0.f;

#define EXPPV(s, v0, v1) { \
    union { f16x8 v; f16x2 h[4]; } _q0, _q1; \
    _Pragma("unroll") \
    for (int i = 0; i < 4; ++i) { \
      float e0 = __builtin_amdgcn_exp2f(s[2 * i]); \
      float e1 = __builtin_amdgcn_exp2f(s[2 * i + 1]); \
      ls0 += e0; ls1 += e1; \
      _q0.h[i] = pkcvt(e0, e1); \
      float e2 = __builtin_amdgcn_exp2f(s[8 + 2 * i]); \
      float e3 = __builtin_amdgcn_exp2f(s[9 + 2 * i]); \
      ls0 += e2; ls1 += e3; \
      _q1.h[i] = pkcvt(e2, e3); \
    } \
    oacc = __builtin_amdgcn_mfma_f32_32x32x16_f16(v0, _q0.v, oacc, 0, 0, 0); \
    oacc = __builtin_amdgcn_mfma_f32_32x32x16_f16(v1, _q1.v, oacc, 0, 0, 0); }

  // prologue: stage tile 0, issue tile 1 loads
  f16x8 gk = *(const f16x8*)gK;
  f16x8 gv = *(const f16x8*)gV;
  *(f16x8*)(&kl[0][lK]) = gk;
  *(f16x8*)(&vl[0][lV]) = gv;
  gk = *(const f16x8*)(gK + 64 * DHEAD);
  gv = *(const f16x8*)(gV + 64);
  __syncthreads();

  for (int t = 0; t < 16; ++t) {
    const f16* kb = kl[t & 1];
    const f16* vb = vl[t & 1];
#pragma unroll
    for (int sub = 0; sub < 2; ++sub) {
      f16x8 kf0 = *(const f16x8*)(kb + (sub * 32 + l32) * TKROW + hi * 8);
      f16x8 kf1 = *(const f16x8*)(kb + (sub * 32 + l32) * TKROW + hi * 8 + 16);
      f16x8 vf0 = *(const f16x8*)(vb + l32 * TVROW + sub * 32 + hi * 8);
      f16x8 vf1 = *(const f16x8*)(vb + l32 * TVROW + sub * 32 + hi * 8 + 16);
      f32x16 s = __builtin_amdgcn_mfma_f32_32x32x16_f16(kf0, qf0, z16, 0, 0, 0);
      s = __builtin_amdgcn_mfma_f32_32x32x16_f16(kf1, qf1, s, 0, 0, 0);
      EXPPV(s, vf0, vf1)
    }
    if (t < 15) {
      __syncthreads();  // all waves done reading buf[(t+1)&1] (tile t-1)
      *(f16x8*)(&kl[(t + 1) & 1][lK]) = gk;
      *(f16x8*)(&vl[(t + 1) & 1][lV]) = gv;
      if (t + 1 < 15) {  // issue tile t+2: covered by tile t+1's compute
        gk = *(const f16x8*)(gK + (size_t)(t + 2) * 64 * DHEAD);
        gv = *(const f16x8*)(gV + (t + 2) * 64);
      }
      __syncthreads();  // buf[(t+1)&1] visible
    }
  }
#undef EXPPV

  float lsum = ls0 + ls1;        // own 16 k-rows
  lsum += __shfl_xor(lsum, 32);  // + partner half's 16 k-rows
  const float inv = __builtin_amdgcn_rcpf(lsum);

  f16* op = xo + hb + (size_t)(qbase + l32) * DHEAD + hi * 4;
#pragma unroll
  for (int g = 0; g < 4; ++g) {   // d-base = 8g + 4hi, 4 contiguous d each
    union { f16x4 v; f16x2 h[2]; } o;
    o.h[0] = pkcvt(oacc[4 * g + 0] * inv, oacc[4 * g + 1] * inv);
    o.h[1] = pkcvt(oacc[4 * g + 2] * inv, oacc[4 * g + 3] * inv);
    *(f16x4*)(op + 8 * g) = o.v;
  }
}

// ---------------------------------------------------------------------------
// Kernel 3: out = xatt @ Wm^T + bm + residual, f32 out, via MFMA.
// Same structure as proj_mfma; A = Wm inline f32->f16; k-step kk == head kk
// of xatt ([bth][l][32] is k-contiguous within a head). float4 stores.
// ---------------------------------------------------------------------------
__global__ __launch_bounds__(256, 3)
void out_proj_mfma_kernel(const f16* __restrict__ xatt,
                          const float* __restrict__ Wm,
                          const float* __restrict__ bm,
                          const float* __restrict__ resid,
                          float* __restrict__ out) {
  const int tid = threadIdx.x;
  const int wave = tid >> 6, lane = tid & 63;
  const int quad = lane >> 4, l16 = lane & 15;
  const int tokbase = blockIdx.x * 64;
  const int wbase = wave * 64;
  const int bt = tokbase >> 10, l0 = tokbase & 1023;

  f32x4 acc[4][4];
#pragma unroll
  for (int mt = 0; mt < 4; ++mt)
#pragma unroll
    for (int nt = 0; nt < 4; ++nt) acc[mt][nt] = (f32x4){0.f, 0.f, 0.f, 0.f};

#pragma unroll
  for (int kk = 0; kk < 8; ++kk) {
    const size_t hb = (size_t)(bt * HEADS + kk) * (LSEQ * DHEAD);
    f16x8 af[4], bf[4];
#pragma unroll
    for (int mt = 0; mt < 4; ++mt)
      af[mt] = cvt8(Wm + (size_t)(wbase + mt * 16 + l16) * CDIM + kk * 32 +
                    quad * 8);
#pragma unroll
    for (int nt = 0; nt < 4; ++nt)
      bf[nt] = *(const f16x8*)(xatt + hb +
                               (size_t)(l0 + nt * 16 + l16) * DHEAD + quad * 8);
#pragma unroll
    for (int mt = 0; mt < 4; ++mt)
#pragma unroll
      for (int nt = 0; nt < 4; ++nt)
        acc[mt][nt] = __builtin_amdgcn_mfma_f32_16x16x32_f16(af[mt], bf[nt],
                                                             acc[mt][nt], 0, 0, 0);
  }

#pragma unroll
  for (int mt = 0; mt < 4; ++mt) {
    float4 bv = *(const float4*)(bm + wbase + mt * 16 + quad * 4);
#pragma unroll
    for (int nt = 0; nt < 4; ++nt) {
      const int tok = tokbase + nt * 16 + l16;
      const size_t off = (size_t)tok * CDIM + wbase + mt * 16 + quad * 4;
      float4 rv = *(const float4*)(resid + off);
      float4 o;
      o.x = acc[mt][nt][0] + bv.x + rv.x;
      o.y = acc[mt][nt][1] + bv.y + rv.y;
      o.z = acc[mt][nt][2] + bv.z + rv.z;
      o.w = acc[mt][nt][3] + bv.w + rv.w;
      *(float4*)(out + off) = o;
    }
  }
}

extern "C" void kernel_launch(void* const* d_in, const int* in_sizes, int n_in,
                              void* d_out, int out_size, void* d_ws,
                              size_t ws_size, hipStream_t stream) {
  const float* q  = (const float*)d_in[0];
  const float* k  = (const float*)d_in[1];
  const float* v  = (const float*)d_in[2];
  const float* Wq = (const float*)d_in[3];
  const float* bq = (const float*)d_in[4];
  const float* Wk = (const float*)d_in[5];
  const float* bk = (const float*)d_in[6];
  const float* Wv = (const float*)d_in[7];
  const float* bv = (const float*)d_in[8];
  const float* Wm = (const float*)d_in[9];
  const float* bm = (const float*)d_in[10];
  float* outp = (float*)d_out;

  f16* ws = (f16*)d_ws;
  const size_t TENS = (size_t)NTOK * CDIM;  // 4194304
  f16* qn  = ws;
  f16* kn  = ws + TENS;
  f16* vt  = ws + 2 * TENS;
  f16* xa  = ws + 3 * TENS;
  f16* w16 = xa;  // alias: consumed by proj_mfma before attn writes xa

  dim3 blk(256);
  cvt_w_kernel<<<dim3(192), blk, 0, stream>>>(Wq, Wk, Wv, w16);
  proj_mfma_kernel<<<dim3(256, 3), blk, 0, stream>>>(q, k, v, w16, bq, bk, bv,
                                                     qn, kn, vt);
  attn_mfma_kernel<<<dim3(1024), blk, 0, stream>>>(qn, kn, vt, xa);
  out_proj_mfma_kernel<<<dim3(256), blk, 0, stream>>>(xa, Wm, bm, q, outp);
}